// Round 10
// baseline (149987.781 us; speedup 1.0000x reference)
//
#include <hip/hip_runtime.h>
#include <hip/hip_bf16.h>
#include <math.h>

// ---------------------------------------------------------------------------
// MyRNN persistent kernel, round 10: XCD-leader broadcast, placement-free.
//   Roles: per ACTUAL XCD (s_getreg HW_REG_XCC_ID), first WG to arrive wins
//   atomicCAS -> leader. Leaders are normal compute WGs that ALSO mirror.
//   Producer: every wave's lane0 fires ONE tagged word ((t+1)<<16|bf16(h))
//     to global hb (agent scope). No tree, no flags, no drains.
//   Leader wave g: tag-polls global slice g (per-lane early exit, s_sleep),
//     mirrors 16B/lane into this XCD's local buffer (plain stores -> local
//     L2), vmcnt-drain, lane0 sets local flag lf[g]=t+1 (plain store).
//   Follower wave g: bounded sc0 poll of lf[g] (same-XCD L2 by construction),
//     sc0 16B read of local slice; on timeout latches WG to the global
//     self-validating tag-poll path (always correct, always terminates).
//
// ws layout (32-bit words):
//   [0,128)        claim[xcd] at word xcd*16 (election lines)
//   [1024,5120)    hb0: 4096 tagged words (h for even t)
//   [5120,9216)    hb1: same (odd t)
//   [16384,147456) per-XCD regions, stride 16384 words:
//                    +0 local parity0 (4096 w), +4096 parity1, +8192 lf[16]*16
//   [147456,...)   xp [256][2048][16] f32 (32 MiB)
// words [0,147456) memset 0 every launch (claim, tags (h_0=0), flags).
// ---------------------------------------------------------------------------

#define T_STEPS  2048
#define INPUT_N  2048
#define HIDDEN_N 4096
#define NWG      256
#define NTHR     1024
#define XBASE    16384
#define XSTRIDE  16384
#define XPBASE   147456

typedef float f32x4 __attribute__((ext_vector_type(4)));
typedef unsigned int uint32;
typedef uint32 u32x4 __attribute__((ext_vector_type(4)));
typedef unsigned long long u64;
typedef unsigned short u16;

__device__ __forceinline__ float wave_reduce(float v) {
#pragma unroll
  for (int off = 32; off > 0; off >>= 1) v += __shfl_xor(v, off, 64);
  return v;
}
__device__ __forceinline__ float bits_to_f(uint32 u) {
  union { uint32 u; float f; } c; c.u = u; return c.f;
}
// L1-bypassing loads (read the XCD-shared L2 coherence point)
__device__ __forceinline__ uint32 load_u32_sc0(const void* p) {
  uint32 v;
  asm volatile("global_load_dword %0, %1, off sc0\ns_waitcnt vmcnt(0)"
               : "=v"(v) : "v"(p) : "memory");
  return v;
}
__device__ __forceinline__ u32x4 load_b128_sc0(const void* p) {
  u32x4 v;
  asm volatile("global_load_dwordx4 %0, %1, off sc0\ns_waitcnt vmcnt(0)"
               : "=v"(v) : "v"(p) : "memory");
  return v;
}

__device__ __forceinline__ void tag_poll_global(const uint32* gsrc, uint32 tgt,
                                                u64& u01, u64& u23) {
  bool d0 = false, d1 = false;
  u01 = 0; u23 = 0;
  for (;;) {
    if (!d0) {
      u01 = __hip_atomic_load((const u64*)gsrc, __ATOMIC_RELAXED,
                              __HIP_MEMORY_SCOPE_AGENT);
      d0 = (((uint32)u01 >> 16) == tgt) &&
           (((uint32)(u01 >> 32) >> 16) == tgt);
    }
    if (!d1) {
      u23 = __hip_atomic_load((const u64*)(gsrc + 2), __ATOMIC_RELAXED,
                              __HIP_MEMORY_SCOPE_AGENT);
      d1 = (((uint32)u23 >> 16) == tgt) &&
           (((uint32)(u23 >> 32) >> 16) == tgt);
    }
    if (__all(d0 && d1)) break;
    __builtin_amdgcn_s_sleep(1);
  }
}
__device__ __forceinline__ f32x4 unpack2(u64 u01, u64 u23) {
  f32x4 p;
  p.x = bits_to_f((uint32)u01 << 16);
  p.y = bits_to_f((uint32)(u01 >> 32) << 16);
  p.z = bits_to_f((uint32)u23 << 16);
  p.w = bits_to_f((uint32)(u23 >> 32) << 16);
  return p;
}

// Stage this lane's 4 rows of h_t (t in [0, T_STEPS]).
__device__ __forceinline__ f32x4 stage_ht(int t, bool lead, int* s_fast_p,
                                          const uint32* hb0, const uint32* hb1,
                                          uint32* lbuf, volatile int* myflag,
                                          int cbase, int lane) {
  const uint32 tgt = (uint32)t;
  const uint32* gsrc = ((t & 1) ? hb1 : hb0) + cbase;
  uint32* lslot = lbuf + (t & 1) * 4096;
  if (lead) {
    u64 u01, u23;
    tag_poll_global(gsrc, tgt, u01, u23);
    u64* ld = (u64*)(lslot + cbase);      // mirror -> local L2 (plain stores)
    ld[0] = u01;
    ld[1] = u23;
    asm volatile("s_waitcnt vmcnt(0)" ::: "memory");  // data in L2
    if (lane == 0) *myflag = t + 1;                   // then flag
    return unpack2(u01, u23);
  }
  if (*s_fast_p) {
    const int lim = (t == 0) ? (1 << 20) : 8192;      // generous at t=0 (skew)
    int it = 0;
    bool got = false;
    for (;;) {
      if ((int)load_u32_sc0((const void*)myflag) >= t + 1) { got = true; break; }
      if (++it > lim) break;
    }
    if (got) {
      u32x4 v = load_b128_sc0(lslot + cbase);
      f32x4 p;
      p.x = bits_to_f(v.x << 16);
      p.y = bits_to_f(v.y << 16);
      p.z = bits_to_f(v.z << 16);
      p.w = bits_to_f(v.w << 16);
      return p;
    }
    *s_fast_p = 0;   // latch WG to global path (benign race)
  }
  u64 u01, u23;
  tag_poll_global(gsrc, tgt, u01, u23);   // self-validating fallback
  return unpack2(u01, u23);
}

__global__ __attribute__((amdgpu_flat_work_group_size(1024, 1024)))
__attribute__((amdgpu_waves_per_eu(4, 4))) void rnn_persistent(
    const float* __restrict__ x,
    const float* __restrict__ wh_w, const float* __restrict__ wh_b,
    const float* __restrict__ wx_w, const float* __restrict__ wx_b,
    const float* __restrict__ wo_w, const float* __restrict__ wo_b,
    float* __restrict__ out, float* __restrict__ ws) {
  const int w    = blockIdx.x;    // owns hidden rows [16w, 16w+16)
  const int tid  = threadIdx.x;
  const int lane = tid & 63;
  const int wv   = tid >> 6;      // wave 0..15 owns row 16w+wv

  int*    claim = (int*)ws;
  uint32* hb0   = (uint32*)(ws + 1024);
  uint32* hb1   = (uint32*)(ws + 5120);
  float*  xp    = ws + XPBASE;

  __shared__ float s_h[HIDDEN_N];
  __shared__ int s_xcc, s_lead, s_fast;

  // ---------------- role discovery (real XCD id + election) ----------------
  if (tid == 0) {
    int xcc;
    asm volatile("s_getreg_b32 %0, hwreg(20, 0, 4)" : "=s"(xcc));  // XCC_ID
    xcc &= 7;
    s_xcc  = xcc;
    s_lead = (atomicCAS(claim + xcc * 16, 0, w + 1) == 0) ? 1 : 0;
    s_fast = 1;
  }
  __syncthreads();
  const int  xcc  = s_xcc;
  const bool lead = (s_lead != 0);
  uint32* lbuf = (uint32*)ws + XBASE + (size_t)xcc * XSTRIDE;
  volatile int* lf = (volatile int*)(lbuf + 8192);
  volatile int* myflag = lf + (wv << 4);

  // ---------------- Phase A: xp = x@Wx^T + bx (WG-private, f32) ------------
  {
    const int tq = lane >> 4;
    const int r  = lane & 15;
    const float* wrow = wx_w + (size_t)(w * 16 + r) * INPUT_N;
    const float  bA   = wx_b[w * 16 + r];
    for (int g = wv; g < 64; g += 16) {
      const int t0 = g * 32 + tq;
      f32x4 acc[8];
      const float* xr[8];
#pragma unroll
      for (int j = 0; j < 8; ++j) {
        acc[j] = (f32x4){0.f, 0.f, 0.f, 0.f};
        xr[j]  = x + (size_t)(t0 + 4 * j) * INPUT_N;
      }
      for (int k = 0; k < 512; ++k) {
        f32x4 wq = *(const f32x4*)(wrow + (size_t)k * 4);
#pragma unroll
        for (int j = 0; j < 8; ++j)
          acc[j] += (*(const f32x4*)(xr[j] + (size_t)k * 4)) * wq;
      }
#pragma unroll
      for (int j = 0; j < 8; ++j) {
        float s = acc[j].x + acc[j].y + acc[j].z + acc[j].w + bA;
        xp[((size_t)w * T_STEPS + (t0 + 4 * j)) * 16 + r] = s;
      }
    }
  }
  __syncthreads();   // xp slice complete (WG-private, same CU)

  // ---------------- Phase B: the scan --------------------------------------
  const float* whrow = wh_w + (size_t)(w * 16 + wv) * HIDDEN_N + lane * 4;
  f32x4 W[16];
#pragma unroll
  for (int i = 0; i < 16; ++i) W[i] = *(const f32x4*)(whrow + i * 256);
  const float bB = wh_b[w * 16 + wv];
  const int   cbase = wv * 256 + 4 * lane;   // my 4 words of the h vector
  const int   pidx  = w * 16 + wv;           // my publish word

  for (int t = 0; t < T_STEPS; ++t) {
    const float xpv = xp[((size_t)w * T_STEPS + t) * 16 + wv];

    // 1) acquire + stage h_t (leader mirrors; follower reads local L2)
    f32x4 p = stage_ht(t, lead, &s_fast, hb0, hb1, lbuf, myflag, cbase, lane);
    *(f32x4*)&s_h[cbase] = p;
    __syncthreads();   // s_h complete

    // 2) own-row dot from LDS against resident W
    f32x4 a0 = {0.f, 0.f, 0.f, 0.f}, a1 = {0.f, 0.f, 0.f, 0.f};
#pragma unroll
    for (int i = 0; i < 16; i += 2) {
      a0 += (*(const f32x4*)&s_h[lane * 4 + i * 256]) * W[i];
      a1 += (*(const f32x4*)&s_h[lane * 4 + (i + 1) * 256]) * W[i + 1];
    }
    float d = wave_reduce(a0.x + a0.y + a0.z + a0.w +
                          a1.x + a1.y + a1.z + a1.w);

    // 3) lane0: tanh -> tagged fire-and-forget publish (entire protocol)
    if (lane == 0) {
      float hn = tanhf(d + bB + xpv);
      __hip_bfloat16 b = __float2bfloat16(hn);
      uint32 word = ((uint32)(t + 1) << 16) | (uint32)(*(u16*)&b);
      uint32* pdst = ((t & 1) ? hb0 : hb1) + pidx;   // parity of t+1
      __hip_atomic_store(pdst, word, __ATOMIC_RELAXED,
                         __HIP_MEMORY_SCOPE_AGENT);
    }
  }

  // ---------------- Phase C: output ----------------------------------------
  {
    f32x4 p = stage_ht(T_STEPS, lead, &s_fast, hb0, hb1, lbuf, myflag,
                       cbase, lane);
    *(f32x4*)&s_h[cbase] = p;
  }
  __syncthreads();
  if (wv < 8) {
    const int o = w * 8 + wv;
    const float* worow = wo_w + (size_t)o * HIDDEN_N + lane * 4;
    f32x4 acc = {0.f, 0.f, 0.f, 0.f};
#pragma unroll
    for (int k = 0; k < 16; ++k)
      acc += (*(const f32x4*)(worow + k * 256)) *
             (*(const f32x4*)&s_h[lane * 4 + k * 256]);
    float s = wave_reduce(acc.x + acc.y + acc.z + acc.w);
    if (lane == 0) {
      float z = s + wo_b[o];
      out[o] = 1.f / (1.f + expf(-z));
    }
  }
}

extern "C" void kernel_launch(void* const* d_in, const int* in_sizes, int n_in,
                              void* d_out, int out_size, void* d_ws,
                              size_t ws_size, hipStream_t stream) {
  const float* x    = (const float*)d_in[0];
  const float* wh_w = (const float*)d_in[1];
  const float* wh_b = (const float*)d_in[2];
  const float* wx_w = (const float*)d_in[3];
  const float* wx_b = (const float*)d_in[4];
  const float* wo_w = (const float*)d_in[5];
  const float* wo_b = (const float*)d_in[6];
  float* out = (float*)d_out;
  float* ws  = (float*)d_ws;

  // claim + tagged h buffers + XCD regions zeroed (tag0 <=> h_0 = 0)
  hipMemsetAsync(d_ws, 0, (size_t)XPBASE * 4, stream);

  hipLaunchKernelGGL(rnn_persistent, dim3(NWG), dim3(NTHR), 0, stream,
                     x, wh_w, wh_b, wx_w, wx_b, wo_w, wo_b, out, ws);
}

// Round 11
// 7593.481 us; speedup vs baseline: 19.7522x; 19.7522x over previous
//
#include <hip/hip_runtime.h>
#include <hip/hip_bf16.h>
#include <math.h>

// ---------------------------------------------------------------------------
// MyRNN persistent kernel, round 11: pure tagged-data sync + timed quiet-wait.
//   Phase A: xp = x@Wx^T + bx (unchanged; WG-private, barrier-free).
//   Phase B: 2048 steps, minimal chain:
//     publish: lane0 fires ONE tagged word ((t+1)<<16 | bf16(h)) per row.
//       That is the ENTIRE protocol: no flags, no counters, no drains.
//     consume: wave wv owns slice wv. It predicts the arrival time of its
//       slice from an EMA of detect-to-detect periods (s_memrealtime),
//       sleeps QUIETLY (no memory traffic) until 3/4 of the period, then
//       tag-polls its 16B/lane with per-lane early-exit + s_sleep(3) retry.
//       Detect and stage are the same read. One barrier per step.
//   Phase C: out = sigmoid(hT @ Wo^T + bo).
//
// ws layout (32-bit words):
//   [1024,5120)  hb0: 4096 tagged words ((t)<<16 | bf16) - h for even t
//   [5120,9216)  hb1: same, odd t
//   [12288,...)  xp [256][2048][16] f32 (32 MiB)
// words [0,9216) memset 0 every launch: tag0 <=> h_0 = 0 (deterministic).
// ---------------------------------------------------------------------------

#define T_STEPS  2048
#define INPUT_N  2048
#define HIDDEN_N 4096
#define NWG      256
#define NTHR     1024

typedef float f32x4 __attribute__((ext_vector_type(4)));
typedef unsigned int uint32;
typedef unsigned long long u64;
typedef unsigned short u16;

__device__ __forceinline__ float wave_reduce(float v) {
#pragma unroll
  for (int off = 32; off > 0; off >>= 1) v += __shfl_xor(v, off, 64);
  return v;
}
__device__ __forceinline__ float bits_to_f(uint32 u) {
  union { uint32 u; float f; } c; c.u = u; return c.f;
}

// Tag-poll this lane's 4 words (2 x 8B agent loads) until all carry tag tgt.
// Per-lane early exit; s_sleep(3) retry (~192cy) caps re-poll traffic.
__device__ __forceinline__ f32x4 tag_poll_stage(const uint32* src,
                                                uint32 tgt) {
  bool d0 = false, d1 = false;
  u64 u01 = 0, u23 = 0;
  for (;;) {
    if (!d0) {
      u01 = __hip_atomic_load((const u64*)src, __ATOMIC_RELAXED,
                              __HIP_MEMORY_SCOPE_AGENT);
      d0 = (((uint32)u01 >> 16) == tgt) &&
           (((uint32)(u01 >> 32) >> 16) == tgt);
    }
    if (!d1) {
      u23 = __hip_atomic_load((const u64*)(src + 2), __ATOMIC_RELAXED,
                              __HIP_MEMORY_SCOPE_AGENT);
      d1 = (((uint32)u23 >> 16) == tgt) &&
           (((uint32)(u23 >> 32) >> 16) == tgt);
    }
    if (__all(d0 && d1)) break;
    __builtin_amdgcn_s_sleep(3);
  }
  f32x4 p;
  p.x = bits_to_f((uint32)u01 << 16);
  p.y = bits_to_f((uint32)(u01 >> 32) << 16);
  p.z = bits_to_f((uint32)u23 << 16);
  p.w = bits_to_f((uint32)(u23 >> 32) << 16);
  return p;
}

__global__ __attribute__((amdgpu_flat_work_group_size(1024, 1024)))
__attribute__((amdgpu_waves_per_eu(4, 4))) void rnn_persistent(
    const float* __restrict__ x,
    const float* __restrict__ wh_w, const float* __restrict__ wh_b,
    const float* __restrict__ wx_w, const float* __restrict__ wx_b,
    const float* __restrict__ wo_w, const float* __restrict__ wo_b,
    float* __restrict__ out, float* __restrict__ ws) {
  const int w    = blockIdx.x;    // owns hidden rows [16w, 16w+16)
  const int tid  = threadIdx.x;
  const int lane = tid & 63;
  const int wv   = tid >> 6;      // wave 0..15 owns row 16w+wv, stages slice wv

  uint32* hb0 = (uint32*)(ws + 1024);   // 4096 tagged words
  uint32* hb1 = (uint32*)(ws + 5120);
  float*  xp  = ws + 12288;             // [w][t][16]

  __shared__ float s_h[HIDDEN_N];   // 16 KiB staged h (f32)

  // ------------------ Phase A: xp (barrier-free, reduce-free) --------------
  {
    const int tq = lane >> 4;        // 0..3
    const int r  = lane & 15;        // row within WG slice
    const float* wrow = wx_w + (size_t)(w * 16 + r) * INPUT_N;
    const float  bA   = wx_b[w * 16 + r];
    for (int g = wv; g < 64; g += 16) {       // 4 groups per wave
      const int t0 = g * 32 + tq;             // t = t0 + 4j, j<8
      f32x4 acc[8];
      const float* xr[8];
#pragma unroll
      for (int j = 0; j < 8; ++j) {
        acc[j] = (f32x4){0.f, 0.f, 0.f, 0.f};
        xr[j]  = x + (size_t)(t0 + 4 * j) * INPUT_N;
      }
      for (int k = 0; k < 512; ++k) {         // 16B granules over K=2048
        f32x4 wq = *(const f32x4*)(wrow + (size_t)k * 4);
#pragma unroll
        for (int j = 0; j < 8; ++j)
          acc[j] += (*(const f32x4*)(xr[j] + (size_t)k * 4)) * wq;
      }
#pragma unroll
      for (int j = 0; j < 8; ++j) {
        float s = acc[j].x + acc[j].y + acc[j].z + acc[j].w + bA;
        xp[((size_t)w * T_STEPS + (t0 + 4 * j)) * 16 + r] = s;
      }
    }
  }
  __syncthreads();   // xp slice complete (WG-private, same CU)

  // ------------------ Phase B: the scan ------------------------------------
  const float* whrow = wh_w + (size_t)(w * 16 + wv) * HIDDEN_N + lane * 4;
  f32x4 W[16];
#pragma unroll
  for (int i = 0; i < 16; ++i) W[i] = *(const f32x4*)(whrow + i * 256);
  const float bB = wh_b[w * 16 + wv];
  const int   cbase = wv * 256 + 4 * lane;   // my 4 words of the h vector
  const int   pidx  = w * 16 + wv;           // my publish word

  // wave-uniform timing state (SALU): EMA of detect-to-detect period
  u64    tprev = 0;
  uint32 P     = 0;        // period estimate in realtime ticks

  for (int t = 0; t < T_STEPS; ++t) {
    const float xpv = xp[((size_t)w * T_STEPS + t) * 16 + wv];

    // 1) quiet wait until ~3/4 of predicted period elapsed (no mem traffic)
    if (t >= 4 && P > 0) {
      const u64 target = tprev + (u64)(P - (P >> 2));
      while (__builtin_amdgcn_s_memrealtime() < target)
        __builtin_amdgcn_s_sleep(2);
    }

    // 2) tag-poll + stage my slice of h_t (detect == stage, same read)
    const uint32* src = ((t & 1) ? hb1 : hb0) + cbase;
    f32x4 p = tag_poll_stage(src, (uint32)t);

    // 3) update the period estimate from this detect
    {
      u64 tnow = __builtin_amdgcn_s_memrealtime();
      u64 dt64 = tnow - tprev;
      if (t > 0 && dt64 < (1ull << 20)) {
        uint32 dt = (uint32)dt64;
        P = P ? ((P * 3 + dt) >> 2) : dt;
      }
      tprev = tnow;
    }

    *(f32x4*)&s_h[cbase] = p;
    __syncthreads();   // single barrier: s_h complete

    // 4) own-row dot from LDS against resident W
    f32x4 a0 = {0.f, 0.f, 0.f, 0.f}, a1 = {0.f, 0.f, 0.f, 0.f};
#pragma unroll
    for (int i = 0; i < 16; i += 2) {
      a0 += (*(const f32x4*)&s_h[lane * 4 + i * 256]) * W[i];
      a1 += (*(const f32x4*)&s_h[lane * 4 + (i + 1) * 256]) * W[i + 1];
    }
    float d = wave_reduce(a0.x + a0.y + a0.z + a0.w +
                          a1.x + a1.y + a1.z + a1.w);

    // 5) lane0: tanh -> tagged fire-and-forget publish (entire protocol)
    if (lane == 0) {
      float hn = tanhf(d + bB + xpv);
      __hip_bfloat16 b = __float2bfloat16(hn);
      uint32 word = ((uint32)(t + 1) << 16) | (uint32)(*(u16*)&b);
      uint32* pdst = ((t & 1) ? hb0 : hb1) + pidx;   // parity of t+1
      __hip_atomic_store(pdst, word, __ATOMIC_RELAXED,
                         __HIP_MEMORY_SCOPE_AGENT);
    }
  }

  // ------------------ Phase C: output --------------------------------------
  {
    const uint32* src = hb0 + cbase;   // h_2048 (tag 2048) in hb[2048&1]=hb0
    f32x4 p = tag_poll_stage(src, (uint32)T_STEPS);
    *(f32x4*)&s_h[cbase] = p;
  }
  __syncthreads();
  if (wv < 8) {
    const int o = w * 8 + wv;
    const float* worow = wo_w + (size_t)o * HIDDEN_N + lane * 4;
    f32x4 acc = {0.f, 0.f, 0.f, 0.f};
#pragma unroll
    for (int k = 0; k < 16; ++k)
      acc += (*(const f32x4*)(worow + k * 256)) *
             (*(const f32x4*)&s_h[lane * 4 + k * 256]);
    float s = wave_reduce(acc.x + acc.y + acc.z + acc.w);
    if (lane == 0) {
      float z = s + wo_b[o];
      out[o] = 1.f / (1.f + expf(-z));
    }
  }
}

extern "C" void kernel_launch(void* const* d_in, const int* in_sizes, int n_in,
                              void* d_out, int out_size, void* d_ws,
                              size_t ws_size, hipStream_t stream) {
  const float* x    = (const float*)d_in[0];
  const float* wh_w = (const float*)d_in[1];
  const float* wh_b = (const float*)d_in[2];
  const float* wx_w = (const float*)d_in[3];
  const float* wx_b = (const float*)d_in[4];
  const float* wo_w = (const float*)d_in[5];
  const float* wo_b = (const float*)d_in[6];
  float* out = (float*)d_out;
  float* ws  = (float*)d_ws;

  // tagged h buffers zeroed every call: tag0 <=> h_0 = 0 (deterministic)
  hipMemsetAsync(d_ws, 0, 9216 * 4, stream);

  hipLaunchKernelGGL(rnn_persistent, dim3(NWG), dim3(NTHR), 0, stream,
                     x, wh_w, wh_b, wx_w, wx_b, wo_w, wo_b, out, ws);
}

// Round 12
// 7445.832 us; speedup vs baseline: 20.1439x; 1.0198x over previous
//
#include <hip/hip_runtime.h>
#include <hip/hip_bf16.h>
#include <math.h>

// ---------------------------------------------------------------------------
// MyRNN persistent kernel, round 12: 1-bit in-word generation tags, 2 rows
// per dword, 8 waves x 2 rows, timed quiet-wait (r11), minimal 2-leg chain.
//   Fact: |tanh| <= 1 -> bf16 bit14 == 0 always. Steal bit14 of each bf16 as
//   a generation bit g = (t>>1)&1 (occupants of one parity buffer alternate).
//   Publish: wave computes rows 2k,2k+1 -> one dword (2 bf16 + 2 tag bits),
//   fire-and-forget store. Consume: wave wv owns 256 dwords; 4 dwords/lane
//   via 2 u64 loads; validate (u & 0x4000400040004000) == expected; EMA
//   quiet-wait before polling. One barrier/step.
//
// ws layout (32-bit words):
//   [1024,3072)  hb0: 2048 packed dwords (h rows 2d,2d+1) - even t
//   [3072,5120)  hb1: same, odd t  (memset BYTE 0x40 -> gen-1 stale)
//   [8192,...)   xp f32 [256][2048][16] (32 MiB)
// hb0 memset 0 (h_0 = 0, gen 0); hb1 memset 0x40 every launch.
// ---------------------------------------------------------------------------

#define T_STEPS  2048
#define INPUT_N  2048
#define HIDDEN_N 4096
#define NWG      256
#define NTHR     512
#define TAGM32   0x40004000u

typedef float f32x4 __attribute__((ext_vector_type(4)));
typedef unsigned int uint32;
typedef unsigned long long u64;
typedef unsigned short u16;

__device__ __forceinline__ float wave_reduce(float v) {
#pragma unroll
  for (int off = 32; off > 0; off >>= 1) v += __shfl_xor(v, off, 64);
  return v;
}
__device__ __forceinline__ float bits_to_f(uint32 u) {
  union { uint32 u; float f; } c; c.u = u; return c.f;
}

__global__ __attribute__((amdgpu_flat_work_group_size(512, 512)))
__attribute__((amdgpu_waves_per_eu(2))) void rnn_persistent(
    const float* __restrict__ x,
    const float* __restrict__ wh_w, const float* __restrict__ wh_b,
    const float* __restrict__ wx_w, const float* __restrict__ wx_b,
    const float* __restrict__ wo_w, const float* __restrict__ wo_b,
    float* __restrict__ out, float* __restrict__ ws) {
  const int w    = blockIdx.x;    // owns hidden rows [16w, 16w+16)
  const int tid  = threadIdx.x;   // 0..511
  const int lane = tid & 63;
  const int wv   = tid >> 6;      // wave 0..7 owns rows 16w+2wv, 16w+2wv+1

  uint32* hb0 = (uint32*)(ws + 1024);   // 2048 packed dwords
  uint32* hb1 = (uint32*)(ws + 3072);
  float*  xp  = ws + 8192;              // [w][t][16]

  __shared__ float s_h[HIDDEN_N];   // 16 KiB staged h (f32)

  // ------------------ Phase A: xp (barrier-free, reduce-free) --------------
  {
    const int tq = lane >> 4;        // 0..3
    const int r  = lane & 15;        // row within WG slice
    const float* wrow = wx_w + (size_t)(w * 16 + r) * INPUT_N;
    const float  bA   = wx_b[w * 16 + r];
    for (int g = wv; g < 64; g += 8) {        // 8 groups per wave
      const int t0 = g * 32 + tq;             // t = t0 + 4j, j<8
      f32x4 acc[8];
      const float* xr[8];
#pragma unroll
      for (int j = 0; j < 8; ++j) {
        acc[j] = (f32x4){0.f, 0.f, 0.f, 0.f};
        xr[j]  = x + (size_t)(t0 + 4 * j) * INPUT_N;
      }
      for (int k = 0; k < 512; ++k) {         // 16B granules over K=2048
        f32x4 wq = *(const f32x4*)(wrow + (size_t)k * 4);
#pragma unroll
        for (int j = 0; j < 8; ++j)
          acc[j] += (*(const f32x4*)(xr[j] + (size_t)k * 4)) * wq;
      }
#pragma unroll
      for (int j = 0; j < 8; ++j) {
        float s = acc[j].x + acc[j].y + acc[j].z + acc[j].w + bA;
        xp[((size_t)w * T_STEPS + (t0 + 4 * j)) * 16 + r] = s;
      }
    }
  }
  __syncthreads();   // xp slice complete (WG-private, same CU)

  // ------------------ Phase B: the scan ------------------------------------
  const int r0 = w * 16 + 2 * wv;
  const float* wr0 = wh_w + (size_t)r0 * HIDDEN_N + lane * 4;
  const float* wr1 = wh_w + (size_t)(r0 + 1) * HIDDEN_N + lane * 4;
  f32x4 W0[16], W1[16];
#pragma unroll
  for (int i = 0; i < 16; ++i) {
    W0[i] = *(const f32x4*)(wr0 + i * 256);
    W1[i] = *(const f32x4*)(wr1 + i * 256);
  }
  const float bB0 = wh_b[r0], bB1 = wh_b[r0 + 1];
  const int   cbase = wv * 256 + lane * 4;   // my 4 packed dwords
  const int   pidx  = w * 8 + wv;            // my publish dword
  const u64   M64   = 0x4000400040004000ull;

  // wave-uniform timing state (SALU): EMA of detect-to-detect period
  u64    tprev = 0;
  uint32 P     = 0;

  for (int t = 0; t < T_STEPS; ++t) {
    const float2 xpv =
        *(const float2*)&xp[((size_t)w * T_STEPS + t) * 16 + 2 * wv];

    // 1) quiet wait until ~3/4 of predicted period elapsed (no mem traffic)
    if (t >= 4 && P > 0) {
      const u64 target = tprev + (u64)(P - (P >> 2));
      while (__builtin_amdgcn_s_memrealtime() < target)
        __builtin_amdgcn_s_sleep(2);
    }

    // 2) tag-poll + stage my 4 dwords of h_t (detect == stage, same read)
    const uint32* src = ((t & 1) ? hb1 : hb0) + cbase;
    const u64 expv = ((t >> 1) & 1) ? M64 : 0ull;
    u64 u01 = 0, u23 = 0;
    {
      bool d0 = false, d1 = false;
      for (;;) {
        if (!d0) {
          u01 = __hip_atomic_load((const u64*)src, __ATOMIC_RELAXED,
                                  __HIP_MEMORY_SCOPE_AGENT);
          d0 = (u01 & M64) == expv;
        }
        if (!d1) {
          u23 = __hip_atomic_load((const u64*)(src + 2), __ATOMIC_RELAXED,
                                  __HIP_MEMORY_SCOPE_AGENT);
          d1 = (u23 & M64) == expv;
        }
        if (__all(d0 && d1)) break;
        __builtin_amdgcn_s_sleep(3);
      }
    }

    // 3) update the period estimate from this detect
    {
      u64 tnow = __builtin_amdgcn_s_memrealtime();
      u64 dt64 = tnow - tprev;
      if (t > 0 && dt64 < (1ull << 20)) {
        uint32 dt = (uint32)dt64;
        P = P ? ((P * 3 + dt) >> 2) : dt;
      }
      tprev = tnow;
    }

    // 4) unpack (clear tag bits) -> LDS
    {
      uint32 w0 = (uint32)u01 & ~TAGM32, w1 = (uint32)(u01 >> 32) & ~TAGM32;
      uint32 w2 = (uint32)u23 & ~TAGM32, w3 = (uint32)(u23 >> 32) & ~TAGM32;
      f32x4 pa, pb;
      pa.x = bits_to_f(w0 << 16);  pa.y = bits_to_f(w0 & 0xffff0000u);
      pa.z = bits_to_f(w1 << 16);  pa.w = bits_to_f(w1 & 0xffff0000u);
      pb.x = bits_to_f(w2 << 16);  pb.y = bits_to_f(w2 & 0xffff0000u);
      pb.z = bits_to_f(w3 << 16);  pb.w = bits_to_f(w3 & 0xffff0000u);
      *(f32x4*)&s_h[2 * cbase]     = pa;
      *(f32x4*)&s_h[2 * cbase + 4] = pb;
    }
    __syncthreads();   // single barrier: s_h complete

    // 5) 2-row dot from LDS against resident weights
    f32x4 a = {0.f, 0.f, 0.f, 0.f}, b = {0.f, 0.f, 0.f, 0.f};
#pragma unroll
    for (int i = 0; i < 16; ++i) {
      f32x4 hv = *(const f32x4*)&s_h[lane * 4 + i * 256];
      a += hv * W0[i];
      b += hv * W1[i];
    }
    float ra = wave_reduce(a.x + a.y + a.z + a.w);
    float rb = wave_reduce(b.x + b.y + b.z + b.w);

    // 6) tanh on lanes 0,1 in parallel; lane0 packs + publishes one dword
    float pre = (lane == 0) ? (ra + bB0 + xpv.x) : (rb + bB1 + xpv.y);
    float hn  = tanhf(pre);
    float h1v = __shfl(hn, 1);
    if (lane == 0) {
      __hip_bfloat16 c0 = __float2bfloat16(hn);
      __hip_bfloat16 c1 = __float2bfloat16(h1v);
      uint32 word = (uint32)(*(u16*)&c0) | ((uint32)(*(u16*)&c1) << 16);
      if (((t + 1) >> 1) & 1) word |= TAGM32;          // generation bits
      uint32* pdst = ((t & 1) ? hb0 : hb1) + pidx;     // parity of t+1
      __hip_atomic_store(pdst, word, __ATOMIC_RELAXED,
                         __HIP_MEMORY_SCOPE_AGENT);    // fire-and-forget
    }
  }

  // ------------------ Phase C: output --------------------------------------
  {
    // h_2048: buffer hb0 (2048&1=0), generation (2048>>1)&1 = 0
    const uint32* src = hb0 + cbase;
    u64 u01 = 0, u23 = 0;
    bool d0 = false, d1 = false;
    for (;;) {
      if (!d0) {
        u01 = __hip_atomic_load((const u64*)src, __ATOMIC_RELAXED,
                                __HIP_MEMORY_SCOPE_AGENT);
        d0 = (u01 & M64) == 0ull;
      }
      if (!d1) {
        u23 = __hip_atomic_load((const u64*)(src + 2), __ATOMIC_RELAXED,
                                __HIP_MEMORY_SCOPE_AGENT);
        d1 = (u23 & M64) == 0ull;
      }
      if (__all(d0 && d1)) break;
      __builtin_amdgcn_s_sleep(3);
    }
    uint32 w0 = (uint32)u01 & ~TAGM32, w1 = (uint32)(u01 >> 32) & ~TAGM32;
    uint32 w2 = (uint32)u23 & ~TAGM32, w3 = (uint32)(u23 >> 32) & ~TAGM32;
    f32x4 pa, pb;
    pa.x = bits_to_f(w0 << 16);  pa.y = bits_to_f(w0 & 0xffff0000u);
    pa.z = bits_to_f(w1 << 16);  pa.w = bits_to_f(w1 & 0xffff0000u);
    pb.x = bits_to_f(w2 << 16);  pb.y = bits_to_f(w2 & 0xffff0000u);
    pb.z = bits_to_f(w3 << 16);  pb.w = bits_to_f(w3 & 0xffff0000u);
    *(f32x4*)&s_h[2 * cbase]     = pa;
    *(f32x4*)&s_h[2 * cbase + 4] = pb;
  }
  __syncthreads();
  {
    const int o = w * 8 + wv;     // 8 outputs per WG, one per wave
    const float* worow = wo_w + (size_t)o * HIDDEN_N + lane * 4;
    f32x4 acc = {0.f, 0.f, 0.f, 0.f};
#pragma unroll
    for (int k = 0; k < 16; ++k)
      acc += (*(const f32x4*)(worow + k * 256)) *
             (*(const f32x4*)&s_h[lane * 4 + k * 256]);
    float s = wave_reduce(acc.x + acc.y + acc.z + acc.w);
    if (lane == 0) {
      float z = s + wo_b[o];
      out[o] = 1.f / (1.f + expf(-z));
    }
  }
}

extern "C" void kernel_launch(void* const* d_in, const int* in_sizes, int n_in,
                              void* d_out, int out_size, void* d_ws,
                              size_t ws_size, hipStream_t stream) {
  const float* x    = (const float*)d_in[0];
  const float* wh_w = (const float*)d_in[1];
  const float* wh_b = (const float*)d_in[2];
  const float* wx_w = (const float*)d_in[3];
  const float* wx_b = (const float*)d_in[4];
  const float* wo_w = (const float*)d_in[5];
  const float* wo_b = (const float*)d_in[6];
  float* out = (float*)d_out;
  float* ws  = (float*)d_ws;

  // hb0 = 0x00 (h_0 = 0, generation 0, immediately valid at t=0);
  // hb1 = 0x40 bytes (generation-1 stale marker for t=1's gen-0 wait).
  hipMemsetAsync((char*)d_ws + 1024 * 4, 0x00, 2048 * 4, stream);
  hipMemsetAsync((char*)d_ws + 3072 * 4, 0x40, 2048 * 4, stream);

  hipLaunchKernelGGL(rnn_persistent, dim3(NWG), dim3(NTHR), 0, stream,
                     x, wh_w, wh_b, wx_w, wx_b, wo_w, wo_b, out, ws);
}

// Round 13
// 7062.354 us; speedup vs baseline: 21.2376x; 1.0543x over previous
//
#include <hip/hip_runtime.h>
#include <hip/hip_bf16.h>
#include <math.h>

// ---------------------------------------------------------------------------
// MyRNN persistent kernel, round 13: r12 + fused phase A + DPP reduces.
//   - No separate phase A: each wave preloads its 2 Wx rows (64 VGPRs) and
//     computes xp[t+2] inside the scan loop AFTER publishing h_{t+1}; the
//     x[t+2] L3 reads + FMAs hide in the EMA quiet-wait idle window.
//     2-deep register ring (xpA/xpB), loop unrolled x2 => static indexing.
//   - Critical-path reduce via DPP (row_shr 1/2/4/8, row_bcast 15/31),
//     ~2x faster than the shfl_xor butterfly.
//   - Everything else = r12: 1-bit generation tags in bf16 bit14, 2 rows per
//     dword, 8 waves x 2 rows, timed quiet-wait, fire-and-forget publish.
//
// ws layout (32-bit words):
//   [1024,3072)  hb0: 2048 packed dwords (h rows 2d,2d+1) - even t
//   [3072,5120)  hb1: same, odd t  (memset BYTE 0x40 -> gen-1 stale)
// hb0 memset 0 (h_0 = 0, gen 0); hb1 memset 0x40 every launch.
// ---------------------------------------------------------------------------

#define T_STEPS  2048
#define INPUT_N  2048
#define HIDDEN_N 4096
#define NWG      256
#define NTHR     512
#define TAGM32   0x40004000u

typedef float f32x4 __attribute__((ext_vector_type(4)));
typedef unsigned int uint32;
typedef unsigned long long u64;
typedef unsigned short u16;

__device__ __forceinline__ float bits_to_f(uint32 u) {
  union { uint32 u; float f; } c; c.u = u; return c.f;
}

// 64-lane sum via DPP; result valid on lane 63.
__device__ __forceinline__ float dpp_reduce63(float v) {
  int r;
  r = __builtin_amdgcn_update_dpp(0, __float_as_int(v), 0x111, 0xf, 0xf, true);
  v += __int_as_float(r);   // row_shr:1
  r = __builtin_amdgcn_update_dpp(0, __float_as_int(v), 0x112, 0xf, 0xf, true);
  v += __int_as_float(r);   // row_shr:2
  r = __builtin_amdgcn_update_dpp(0, __float_as_int(v), 0x114, 0xf, 0xf, true);
  v += __int_as_float(r);   // row_shr:4
  r = __builtin_amdgcn_update_dpp(0, __float_as_int(v), 0x118, 0xf, 0xf, true);
  v += __int_as_float(r);   // row_shr:8  -> lane15 of each row = row sum
  r = __builtin_amdgcn_update_dpp(0, __float_as_int(v), 0x142, 0xf, 0xf, true);
  v += __int_as_float(r);   // row_bcast:15 -> lane31 = r0+r1, lane63 = r2+r3
  r = __builtin_amdgcn_update_dpp(0, __float_as_int(v), 0x143, 0xf, 0xf, true);
  v += __int_as_float(r);   // row_bcast:31 -> lane63 = total
  return v;
}

__global__ __attribute__((amdgpu_flat_work_group_size(512, 512)))
__attribute__((amdgpu_waves_per_eu(2))) void rnn_persistent(
    const float* __restrict__ x,
    const float* __restrict__ wh_w, const float* __restrict__ wh_b,
    const float* __restrict__ wx_w, const float* __restrict__ wx_b,
    const float* __restrict__ wo_w, const float* __restrict__ wo_b,
    float* __restrict__ out, float* __restrict__ ws) {
  const int w    = blockIdx.x;    // owns hidden rows [16w, 16w+16)
  const int tid  = threadIdx.x;   // 0..511
  const int lane = tid & 63;
  const int wv   = tid >> 6;      // wave 0..7 owns rows 16w+2wv, 16w+2wv+1

  uint32* hb0 = (uint32*)(ws + 1024);   // 2048 packed dwords
  uint32* hb1 = (uint32*)(ws + 3072);

  __shared__ float s_h[HIDDEN_N];   // 16 KiB staged h (f32)

  // ---------------- resident weights ---------------------------------------
  const int r0 = w * 16 + 2 * wv;
  const float* wr0 = wh_w + (size_t)r0 * HIDDEN_N + lane * 4;
  const float* wr1 = wh_w + (size_t)(r0 + 1) * HIDDEN_N + lane * 4;
  f32x4 W0[16], W1[16];
#pragma unroll
  for (int i = 0; i < 16; ++i) {
    W0[i] = *(const f32x4*)(wr0 + i * 256);
    W1[i] = *(const f32x4*)(wr1 + i * 256);
  }
  const float* xr0 = wx_w + (size_t)r0 * INPUT_N + lane * 4;
  const float* xr1 = wx_w + (size_t)(r0 + 1) * INPUT_N + lane * 4;
  f32x4 WX0[8], WX1[8];
#pragma unroll
  for (int j = 0; j < 8; ++j) {
    WX0[j] = *(const f32x4*)(xr0 + j * 256);
    WX1[j] = *(const f32x4*)(xr1 + j * 256);
  }
  const float bB0 = wh_b[r0], bB1 = wh_b[r0 + 1];
  const float bA0 = wx_b[r0], bA1 = wx_b[r0 + 1];
  const int   cbase = wv * 256 + lane * 4;   // my 4 packed dwords
  const int   pidx  = w * 8 + wv;            // my publish dword
  const u64   M64   = 0x4000400040004000ull;

  // xp(t) for this wave's 2 rows, all lanes (DPP reduce + bcast from 63)
  auto compute_xp = [&](int tt) -> float2 {
    const float* xrow = x + (size_t)tt * INPUT_N + lane * 4;
    f32x4 a = {0.f, 0.f, 0.f, 0.f}, b = {0.f, 0.f, 0.f, 0.f};
#pragma unroll
    for (int j = 0; j < 8; ++j) {
      f32x4 xv = *(const f32x4*)(xrow + j * 256);
      a += xv * WX0[j];
      b += xv * WX1[j];
    }
    float ra = dpp_reduce63(a.x + a.y + a.z + a.w);
    float rb = dpp_reduce63(b.x + b.y + b.z + b.w);
    float2 res;
    res.x = __shfl(ra, 63) + bA0;
    res.y = __shfl(rb, 63) + bA1;
    return res;
  };

  // wave-uniform timing state (SALU): EMA of detect-to-detect period
  u64    tprev = 0;
  uint32 P     = 0;

  // one full RNN step; xpv = xp for this t (already includes wx bias)
  auto step = [&](int t, const uint32* hbsrc, uint32* hbdst, u64 expv,
                  uint32 pubtag, float2 xpv) {
    // 1) quiet wait until ~3/4 of predicted period elapsed
    if (t >= 4 && P > 0) {
      const u64 target = tprev + (u64)(P - (P >> 2));
      while (__builtin_amdgcn_s_memrealtime() < target)
        __builtin_amdgcn_s_sleep(2);
    }
    // 2) tag-poll + stage my 4 dwords of h_t
    const uint32* src = hbsrc + cbase;
    u64 u01 = 0, u23 = 0;
    {
      bool d0 = false, d1 = false;
      for (;;) {
        if (!d0) {
          u01 = __hip_atomic_load((const u64*)src, __ATOMIC_RELAXED,
                                  __HIP_MEMORY_SCOPE_AGENT);
          d0 = (u01 & M64) == expv;
        }
        if (!d1) {
          u23 = __hip_atomic_load((const u64*)(src + 2), __ATOMIC_RELAXED,
                                  __HIP_MEMORY_SCOPE_AGENT);
          d1 = (u23 & M64) == expv;
        }
        if (__all(d0 && d1)) break;
        __builtin_amdgcn_s_sleep(2);
      }
    }
    // 3) EMA update
    {
      u64 tnow = __builtin_amdgcn_s_memrealtime();
      u64 dt64 = tnow - tprev;
      if (t > 0 && dt64 < (1ull << 20)) {
        uint32 dt = (uint32)dt64;
        P = P ? ((P * 3 + dt) >> 2) : dt;
      }
      tprev = tnow;
    }
    // 4) unpack (clear tag bits) -> LDS
    {
      uint32 w0 = (uint32)u01 & ~TAGM32, w1 = (uint32)(u01 >> 32) & ~TAGM32;
      uint32 w2 = (uint32)u23 & ~TAGM32, w3 = (uint32)(u23 >> 32) & ~TAGM32;
      f32x4 pa, pb;
      pa.x = bits_to_f(w0 << 16);  pa.y = bits_to_f(w0 & 0xffff0000u);
      pa.z = bits_to_f(w1 << 16);  pa.w = bits_to_f(w1 & 0xffff0000u);
      pb.x = bits_to_f(w2 << 16);  pb.y = bits_to_f(w2 & 0xffff0000u);
      pb.z = bits_to_f(w3 << 16);  pb.w = bits_to_f(w3 & 0xffff0000u);
      *(f32x4*)&s_h[2 * cbase]     = pa;
      *(f32x4*)&s_h[2 * cbase + 4] = pb;
    }
    __syncthreads();
    // 5) 2-row dot from LDS against resident Wh
    f32x4 a = {0.f, 0.f, 0.f, 0.f}, b = {0.f, 0.f, 0.f, 0.f};
#pragma unroll
    for (int i = 0; i < 16; ++i) {
      f32x4 hv = *(const f32x4*)&s_h[lane * 4 + i * 256];
      a += hv * W0[i];
      b += hv * W1[i];
    }
    float ra = __shfl(dpp_reduce63(a.x + a.y + a.z + a.w), 63);
    float rb = __shfl(dpp_reduce63(b.x + b.y + b.z + b.w), 63);
    // 6) tanh on lanes 0,1 in parallel; lane0 packs + publishes one dword
    float pre = (lane == 0) ? (ra + bB0 + xpv.x) : (rb + bB1 + xpv.y);
    float hn  = tanhf(pre);
    float h1v = __shfl(hn, 1);
    if (lane == 0) {
      __hip_bfloat16 c0 = __float2bfloat16(hn);
      __hip_bfloat16 c1 = __float2bfloat16(h1v);
      uint32 word = (uint32)(*(u16*)&c0) | ((uint32)(*(u16*)&c1) << 16);
      word |= pubtag;
      __hip_atomic_store(hbdst + pidx, word, __ATOMIC_RELAXED,
                         __HIP_MEMORY_SCOPE_AGENT);    // fire-and-forget
    }
  };

  // ---------------- prologue: xp ring for t=0,1 ----------------------------
  float2 xpA = compute_xp(0);
  float2 xpB = compute_xp(1);

  // ---------------- the scan (unrolled x2: static ring/parity) -------------
  for (int t2 = 0; t2 < T_STEPS; t2 += 2) {
    const int g = (t2 >> 1) & 1;             // generation of h_t2 and h_{t2+1}
    const u64   expv  = g ? M64 : 0ull;
    const uint32 tagA = g ? TAGM32 : 0u;     // h_{t2+1} carries gen g
    const uint32 tagB = g ? 0u : TAGM32;     // h_{t2+2} carries gen !g

    step(t2,     hb0, hb1, expv, tagA, xpA);
    if (t2 + 2 < T_STEPS) xpA = compute_xp(t2 + 2);
    step(t2 + 1, hb1, hb0, expv, tagB, xpB);
    if (t2 + 3 < T_STEPS) xpB = compute_xp(t2 + 3);
  }

  // ---------------- output: sigmoid(hT @ Wo^T + bo) ------------------------
  {
    // h_2048: buffer hb0 (2048&1=0), generation (2048>>1)&1 = 0
    const uint32* src = hb0 + cbase;
    u64 u01 = 0, u23 = 0;
    bool d0 = false, d1 = false;
    for (;;) {
      if (!d0) {
        u01 = __hip_atomic_load((const u64*)src, __ATOMIC_RELAXED,
                                __HIP_MEMORY_SCOPE_AGENT);
        d0 = (u01 & M64) == 0ull;
      }
      if (!d1) {
        u23 = __hip_atomic_load((const u64*)(src + 2), __ATOMIC_RELAXED,
                                __HIP_MEMORY_SCOPE_AGENT);
        d1 = (u23 & M64) == 0ull;
      }
      if (__all(d0 && d1)) break;
      __builtin_amdgcn_s_sleep(2);
    }
    uint32 w0 = (uint32)u01 & ~TAGM32, w1 = (uint32)(u01 >> 32) & ~TAGM32;
    uint32 w2 = (uint32)u23 & ~TAGM32, w3 = (uint32)(u23 >> 32) & ~TAGM32;
    f32x4 pa, pb;
    pa.x = bits_to_f(w0 << 16);  pa.y = bits_to_f(w0 & 0xffff0000u);
    pa.z = bits_to_f(w1 << 16);  pa.w = bits_to_f(w1 & 0xffff0000u);
    pb.x = bits_to_f(w2 << 16);  pb.y = bits_to_f(w2 & 0xffff0000u);
    pb.z = bits_to_f(w3 << 16);  pb.w = bits_to_f(w3 & 0xffff0000u);
    *(f32x4*)&s_h[2 * cbase]     = pa;
    *(f32x4*)&s_h[2 * cbase + 4] = pb;
  }
  __syncthreads();
  {
    const int o = w * 8 + wv;     // 8 outputs per WG, one per wave
    const float* worow = wo_w + (size_t)o * HIDDEN_N + lane * 4;
    f32x4 acc = {0.f, 0.f, 0.f, 0.f};
#pragma unroll
    for (int k = 0; k < 16; ++k)
      acc += (*(const f32x4*)(worow + k * 256)) *
             (*(const f32x4*)&s_h[lane * 4 + k * 256]);
    float s = __shfl(dpp_reduce63(acc.x + acc.y + acc.z + acc.w), 63);
    if (lane == 0) {
      float z = s + wo_b[o];
      out[o] = 1.f / (1.f + expf(-z));
    }
  }
}

extern "C" void kernel_launch(void* const* d_in, const int* in_sizes, int n_in,
                              void* d_out, int out_size, void* d_ws,
                              size_t ws_size, hipStream_t stream) {
  const float* x    = (const float*)d_in[0];
  const float* wh_w = (const float*)d_in[1];
  const float* wh_b = (const float*)d_in[2];
  const float* wx_w = (const float*)d_in[3];
  const float* wx_b = (const float*)d_in[4];
  const float* wo_w = (const float*)d_in[5];
  const float* wo_b = (const float*)d_in[6];
  float* out = (float*)d_out;
  float* ws  = (float*)d_ws;

  // hb0 = 0x00 (h_0 = 0, generation 0, immediately valid at t=0);
  // hb1 = 0x40 bytes (generation-1 stale marker for t=1's gen-0 wait).
  hipMemsetAsync((char*)d_ws + 1024 * 4, 0x00, 2048 * 4, stream);
  hipMemsetAsync((char*)d_ws + 3072 * 4, 0x40, 2048 * 4, stream);

  hipLaunchKernelGGL(rnn_persistent, dim3(NWG), dim3(NTHR), 0, stream,
                     x, wh_w, wh_b, wx_w, wx_b, wo_w, wo_b, out, ws);
}

// Round 14
// 6845.918 us; speedup vs baseline: 21.9091x; 1.0316x over previous
//
#include <hip/hip_runtime.h>
#include <hip/hip_bf16.h>
#include <math.h>

// ---------------------------------------------------------------------------
// MyRNN persistent kernel, round 14: r13 + critical-path micro-shave.
//   - fast tanh: 1 - 2*rcp(1+exp(2x)) (v_exp+v_rcp, ~8 instrs vs libm ~40)
//   - poll retry s_sleep(1) (64cy quantum); quiet-wake at tprev + P/2
//   - EMA arithmetic moved after the LDS write (off the detect->barrier path)
//   Everything else = r13: fused xp (no phase A), DPP reduces, 1-bit
//   generation tags in bf16 bit14, 2 rows/dword, 8 waves x 2 rows,
//   fire-and-forget publish, one barrier/step.
//
// ws layout (32-bit words):
//   [1024,3072)  hb0: 2048 packed dwords (h rows 2d,2d+1) - even t
//   [3072,5120)  hb1: same, odd t  (memset BYTE 0x40 -> gen-1 stale)
// hb0 memset 0 (h_0 = 0, gen 0); hb1 memset 0x40 every launch.
// ---------------------------------------------------------------------------

#define T_STEPS  2048
#define INPUT_N  2048
#define HIDDEN_N 4096
#define NWG      256
#define NTHR     512
#define TAGM32   0x40004000u

typedef float f32x4 __attribute__((ext_vector_type(4)));
typedef unsigned int uint32;
typedef unsigned long long u64;
typedef unsigned short u16;

__device__ __forceinline__ float bits_to_f(uint32 u) {
  union { uint32 u; float f; } c; c.u = u; return c.f;
}

// tanh via hardware exp+rcp: exact at 0 and +-inf; ~1e-6 abs error.
__device__ __forceinline__ float fast_tanh(float x) {
  float e = __expf(2.f * x);
  return 1.f - 2.f * __builtin_amdgcn_rcpf(e + 1.f);
}

// 64-lane sum via DPP; result valid on lane 63.
__device__ __forceinline__ float dpp_reduce63(float v) {
  int r;
  r = __builtin_amdgcn_update_dpp(0, __float_as_int(v), 0x111, 0xf, 0xf, true);
  v += __int_as_float(r);   // row_shr:1
  r = __builtin_amdgcn_update_dpp(0, __float_as_int(v), 0x112, 0xf, 0xf, true);
  v += __int_as_float(r);   // row_shr:2
  r = __builtin_amdgcn_update_dpp(0, __float_as_int(v), 0x114, 0xf, 0xf, true);
  v += __int_as_float(r);   // row_shr:4
  r = __builtin_amdgcn_update_dpp(0, __float_as_int(v), 0x118, 0xf, 0xf, true);
  v += __int_as_float(r);   // row_shr:8  -> lane15 of each row = row sum
  r = __builtin_amdgcn_update_dpp(0, __float_as_int(v), 0x142, 0xf, 0xf, true);
  v += __int_as_float(r);   // row_bcast:15
  r = __builtin_amdgcn_update_dpp(0, __float_as_int(v), 0x143, 0xf, 0xf, true);
  v += __int_as_float(r);   // row_bcast:31 -> lane63 = total
  return v;
}

__global__ __attribute__((amdgpu_flat_work_group_size(512, 512)))
__attribute__((amdgpu_waves_per_eu(2))) void rnn_persistent(
    const float* __restrict__ x,
    const float* __restrict__ wh_w, const float* __restrict__ wh_b,
    const float* __restrict__ wx_w, const float* __restrict__ wx_b,
    const float* __restrict__ wo_w, const float* __restrict__ wo_b,
    float* __restrict__ out, float* __restrict__ ws) {
  const int w    = blockIdx.x;    // owns hidden rows [16w, 16w+16)
  const int tid  = threadIdx.x;   // 0..511
  const int lane = tid & 63;
  const int wv   = tid >> 6;      // wave 0..7 owns rows 16w+2wv, 16w+2wv+1

  uint32* hb0 = (uint32*)(ws + 1024);   // 2048 packed dwords
  uint32* hb1 = (uint32*)(ws + 3072);

  __shared__ float s_h[HIDDEN_N];   // 16 KiB staged h (f32)

  // ---------------- resident weights ---------------------------------------
  const int r0 = w * 16 + 2 * wv;
  const float* wr0 = wh_w + (size_t)r0 * HIDDEN_N + lane * 4;
  const float* wr1 = wh_w + (size_t)(r0 + 1) * HIDDEN_N + lane * 4;
  f32x4 W0[16], W1[16];
#pragma unroll
  for (int i = 0; i < 16; ++i) {
    W0[i] = *(const f32x4*)(wr0 + i * 256);
    W1[i] = *(const f32x4*)(wr1 + i * 256);
  }
  const float* xr0 = wx_w + (size_t)r0 * INPUT_N + lane * 4;
  const float* xr1 = wx_w + (size_t)(r0 + 1) * INPUT_N + lane * 4;
  f32x4 WX0[8], WX1[8];
#pragma unroll
  for (int j = 0; j < 8; ++j) {
    WX0[j] = *(const f32x4*)(xr0 + j * 256);
    WX1[j] = *(const f32x4*)(xr1 + j * 256);
  }
  const float bB0 = wh_b[r0], bB1 = wh_b[r0 + 1];
  const float bA0 = wx_b[r0], bA1 = wx_b[r0 + 1];
  const int   cbase = wv * 256 + lane * 4;   // my 4 packed dwords
  const int   pidx  = w * 8 + wv;            // my publish dword
  const u64   M64   = 0x4000400040004000ull;

  // xp(t) for this wave's 2 rows, all lanes (DPP reduce + bcast from 63)
  auto compute_xp = [&](int tt) -> float2 {
    const float* xrow = x + (size_t)tt * INPUT_N + lane * 4;
    f32x4 a = {0.f, 0.f, 0.f, 0.f}, b = {0.f, 0.f, 0.f, 0.f};
#pragma unroll
    for (int j = 0; j < 8; ++j) {
      f32x4 xv = *(const f32x4*)(xrow + j * 256);
      a += xv * WX0[j];
      b += xv * WX1[j];
    }
    float ra = dpp_reduce63(a.x + a.y + a.z + a.w);
    float rb = dpp_reduce63(b.x + b.y + b.z + b.w);
    float2 res;
    res.x = __shfl(ra, 63) + bA0;
    res.y = __shfl(rb, 63) + bA1;
    return res;
  };

  // wave-uniform timing state (SALU): EMA of detect-to-detect period
  u64    tprev = 0;
  uint32 P     = 0;

  auto step = [&](int t, const uint32* hbsrc, uint32* hbdst, u64 expv,
                  uint32 pubtag, float2 xpv) {
    // 1) quiet wait until ~1/2 of predicted period elapsed (no mem traffic;
    //    wake early enough to never miss the arrival)
    if (t >= 4 && P > 0) {
      const u64 target = tprev + (u64)(P >> 1);
      while (__builtin_amdgcn_s_memrealtime() < target)
        __builtin_amdgcn_s_sleep(2);
    }
    // 2) tag-poll + stage my 4 dwords of h_t (64cy retry quantum)
    const uint32* src = hbsrc + cbase;
    u64 u01 = 0, u23 = 0;
    {
      bool d0 = false, d1 = false;
      for (;;) {
        if (!d0) {
          u01 = __hip_atomic_load((const u64*)src, __ATOMIC_RELAXED,
                                  __HIP_MEMORY_SCOPE_AGENT);
          d0 = (u01 & M64) == expv;
        }
        if (!d1) {
          u23 = __hip_atomic_load((const u64*)(src + 2), __ATOMIC_RELAXED,
                                  __HIP_MEMORY_SCOPE_AGENT);
          d1 = (u23 & M64) == expv;
        }
        if (__all(d0 && d1)) break;
        __builtin_amdgcn_s_sleep(1);
      }
    }
    const u64 tnow = __builtin_amdgcn_s_memrealtime();   // capture only
    // 3) unpack (clear tag bits) -> LDS
    {
      uint32 w0 = (uint32)u01 & ~TAGM32, w1 = (uint32)(u01 >> 32) & ~TAGM32;
      uint32 w2 = (uint32)u23 & ~TAGM32, w3 = (uint32)(u23 >> 32) & ~TAGM32;
      f32x4 pa, pb;
      pa.x = bits_to_f(w0 << 16);  pa.y = bits_to_f(w0 & 0xffff0000u);
      pa.z = bits_to_f(w1 << 16);  pa.w = bits_to_f(w1 & 0xffff0000u);
      pb.x = bits_to_f(w2 << 16);  pb.y = bits_to_f(w2 & 0xffff0000u);
      pb.z = bits_to_f(w3 << 16);  pb.w = bits_to_f(w3 & 0xffff0000u);
      *(f32x4*)&s_h[2 * cbase]     = pa;
      *(f32x4*)&s_h[2 * cbase + 4] = pb;
    }
    // 4) EMA update (overlaps straggler waves' detect; off the hot path)
    {
      u64 dt64 = tnow - tprev;
      if (t > 0 && dt64 < (1ull << 20)) {
        uint32 dt = (uint32)dt64;
        P = P ? ((P * 3 + dt) >> 2) : dt;
      }
      tprev = tnow;
    }
    __syncthreads();
    // 5) 2-row dot from LDS against resident Wh
    f32x4 a = {0.f, 0.f, 0.f, 0.f}, b = {0.f, 0.f, 0.f, 0.f};
#pragma unroll
    for (int i = 0; i < 16; ++i) {
      f32x4 hv = *(const f32x4*)&s_h[lane * 4 + i * 256];
      a += hv * W0[i];
      b += hv * W1[i];
    }
    float ra = __shfl(dpp_reduce63(a.x + a.y + a.z + a.w), 63);
    float rb = __shfl(dpp_reduce63(b.x + b.y + b.z + b.w), 63);
    // 6) fast tanh on lanes 0,1 in parallel; lane0 packs + publishes
    float pre = (lane == 0) ? (ra + bB0 + xpv.x) : (rb + bB1 + xpv.y);
    float hn  = fast_tanh(pre);
    float h1v = __shfl(hn, 1);
    if (lane == 0) {
      __hip_bfloat16 c0 = __float2bfloat16(hn);
      __hip_bfloat16 c1 = __float2bfloat16(h1v);
      uint32 word = (uint32)(*(u16*)&c0) | ((uint32)(*(u16*)&c1) << 16);
      word |= pubtag;
      __hip_atomic_store(hbdst + pidx, word, __ATOMIC_RELAXED,
                         __HIP_MEMORY_SCOPE_AGENT);    // fire-and-forget
    }
  };

  // ---------------- prologue: xp ring for t=0,1 ----------------------------
  float2 xpA = compute_xp(0);
  float2 xpB = compute_xp(1);

  // ---------------- the scan (unrolled x2: static ring/parity) -------------
  for (int t2 = 0; t2 < T_STEPS; t2 += 2) {
    const int g = (t2 >> 1) & 1;             // generation of h_t2 and h_{t2+1}
    const u64   expv  = g ? M64 : 0ull;
    const uint32 tagA = g ? TAGM32 : 0u;     // h_{t2+1} carries gen g
    const uint32 tagB = g ? 0u : TAGM32;     // h_{t2+2} carries gen !g

    step(t2,     hb0, hb1, expv, tagA, xpA);
    if (t2 + 2 < T_STEPS) xpA = compute_xp(t2 + 2);
    step(t2 + 1, hb1, hb0, expv, tagB, xpB);
    if (t2 + 3 < T_STEPS) xpB = compute_xp(t2 + 3);
  }

  // ---------------- output: sigmoid(hT @ Wo^T + bo) ------------------------
  {
    // h_2048: buffer hb0 (2048&1=0), generation (2048>>1)&1 = 0
    const uint32* src = hb0 + cbase;
    u64 u01 = 0, u23 = 0;
    bool d0 = false, d1 = false;
    for (;;) {
      if (!d0) {
        u01 = __hip_atomic_load((const u64*)src, __ATOMIC_RELAXED,
                                __HIP_MEMORY_SCOPE_AGENT);
        d0 = (u01 & M64) == 0ull;
      }
      if (!d1) {
        u23 = __hip_atomic_load((const u64*)(src + 2), __ATOMIC_RELAXED,
                                __HIP_MEMORY_SCOPE_AGENT);
        d1 = (u23 & M64) == 0ull;
      }
      if (__all(d0 && d1)) break;
      __builtin_amdgcn_s_sleep(1);
    }
    uint32 w0 = (uint32)u01 & ~TAGM32, w1 = (uint32)(u01 >> 32) & ~TAGM32;
    uint32 w2 = (uint32)u23 & ~TAGM32, w3 = (uint32)(u23 >> 32) & ~TAGM32;
    f32x4 pa, pb;
    pa.x = bits_to_f(w0 << 16);  pa.y = bits_to_f(w0 & 0xffff0000u);
    pa.z = bits_to_f(w1 << 16);  pa.w = bits_to_f(w1 & 0xffff0000u);
    pb.x = bits_to_f(w2 << 16);  pb.y = bits_to_f(w2 & 0xffff0000u);
    pb.z = bits_to_f(w3 << 16);  pb.w = bits_to_f(w3 & 0xffff0000u);
    *(f32x4*)&s_h[2 * cbase]     = pa;
    *(f32x4*)&s_h[2 * cbase + 4] = pb;
  }
  __syncthreads();
  {
    const int o = w * 8 + wv;     // 8 outputs per WG, one per wave
    const float* worow = wo_w + (size_t)o * HIDDEN_N + lane * 4;
    f32x4 acc = {0.f, 0.f, 0.f, 0.f};
#pragma unroll
    for (int k = 0; k < 16; ++k)
      acc += (*(const f32x4*)(worow + k * 256)) *
             (*(const f32x4*)&s_h[lane * 4 + k * 256]);
    float s = __shfl(dpp_reduce63(acc.x + acc.y + acc.z + acc.w), 63);
    if (lane == 0) {
      float z = s + wo_b[o];
      out[o] = 1.f / (1.f + expf(-z));
    }
  }
}

extern "C" void kernel_launch(void* const* d_in, const int* in_sizes, int n_in,
                              void* d_out, int out_size, void* d_ws,
                              size_t ws_size, hipStream_t stream) {
  const float* x    = (const float*)d_in[0];
  const float* wh_w = (const float*)d_in[1];
  const float* wh_b = (const float*)d_in[2];
  const float* wx_w = (const float*)d_in[3];
  const float* wx_b = (const float*)d_in[4];
  const float* wo_w = (const float*)d_in[5];
  const float* wo_b = (const float*)d_in[6];
  float* out = (float*)d_out;
  float* ws  = (float*)d_ws;

  // hb0 = 0x00 (h_0 = 0, generation 0, immediately valid at t=0);
  // hb1 = 0x40 bytes (generation-1 stale marker for t=1's gen-0 wait).
  hipMemsetAsync((char*)d_ws + 1024 * 4, 0x00, 2048 * 4, stream);
  hipMemsetAsync((char*)d_ws + 3072 * 4, 0x40, 2048 * 4, stream);

  hipLaunchKernelGGL(rnn_persistent, dim3(NWG), dim3(NTHR), 0, stream,
                     x, wh_w, wh_b, wx_w, wx_b, wo_w, wo_b, out, ws);
}